// Round 5
// baseline (147.957 us; speedup 1.0000x reference)
//
#include <hip/hip_runtime.h>

// out = conv2d(poly(img), W, stride=1, pad=1) / 27, poly(v) = A0 + A1*v + A2*v^2
// (identity-kernel branch contributes exactly zero; 1/27 folded into poly).
// Implicit GEMM on bf16 MFMA: A = weights (M=o), B = poly(img) (N = spatial x),
// K = (ky,kx,c) = 576, mfma_f32_32x32x16_bf16.
//
// R5: real software pipeline. Per 16-channel chunk: issue global loads into
// REGISTERS (no wait), run compute(prev chunk) while loads fly, then poly +
// ds_write, then issue(next). 256-thr blocks, 2-row tile, 3 blocks/CU.

typedef __bf16 bf16;
typedef __attribute__((ext_vector_type(8))) __bf16 bf16x8;
typedef __attribute__((ext_vector_type(16))) float f32x16;

static constexpr float A0 = -0.000287f / 27.0f;
static constexpr float A1 =  0.266f    / 27.0f;
static constexpr float A2 = -0.1097f   / 27.0f;

#define NN 16
#define CI 64
#define HH 128
#define WW 128
#define OO 64
#define HW (HH * WW)

// Repack weights [O][C][3][3] fp32 -> [slice=ky*3+kx][cc8=c/8][o][cj=c%8] bf16.
__global__ void repack_w(const float* __restrict__ w, bf16* __restrict__ wrb) {
    int idx = blockIdx.x * 256 + threadIdx.x;        // 9*8*64*8 = 36864
    if (idx >= 9 * 8 * 64 * 8) return;
    int cj    = idx & 7;
    int o     = (idx >> 3) & 63;
    int cc8   = (idx >> 9) & 7;
    int slice = idx >> 12;
    int ky = slice / 3, kx = slice - ky * 3;
    int c = cc8 * 8 + cj;
    wrb[idx] = (bf16)w[((o * CI + c) * 3 + ky) * 3 + kx];
}

// Block: (n, 2 output rows), 256 threads = 4 waves.
// Wave wv: yl = wv>>1 (output row), Xh = (wv&1)*64. 2 o-tiles x 2 x-tiles each.
__global__ __launch_bounds__(256, 3) void conv_mfma(const float* __restrict__ img,
                                                    const bf16* __restrict__ wrb,
                                                    float* __restrict__ out) {
    // Staging: [buf 2][r 4][ccl 2][xp 130][cj 8] bf16, buf stride 8320 elem.
    // Epilogue reuses bytes [0,16384) as [o16 16][y 2][x 128] f32.
    __shared__ __align__(16) bf16 ilds[2 * 4 * 2 * 130 * 8];
    float* elds = (float*)ilds;

    const int tid = threadIdx.x;
    const int b   = blockIdx.x;
    const int y0  = (b & 63) * 2;
    const int n   = b >> 6;

    const int wv   = tid >> 6;
    const int lane = tid & 63;
    const int lm   = lane & 31;      // A: o-row / B: x-col / C: col
    const int half = lane >> 5;      // k-half (which cc8 of the chunk pair)
    const int yl   = wv >> 1;
    const int Xh   = (wv & 1) * 64;

    // Staging decomposition: exactly 256 items = (r 4) x (ccl 2) x (xq 32).
    const int sxq  = tid & 31;
    const int sccl = (tid >> 5) & 1;
    const int sr   = tid >> 6;
    const int syi  = y0 - 1 + sr;
    const bool sval = (unsigned)syi < 128u;
    const float* sbase = img + ((n * CI + sccl * 8) * HH + (sval ? syi : 0)) * WW + 4 * sxq;
    bf16* srow = ilds + (sr * 2 + sccl) * (130 * 8) + (4 * sxq + 1) * 8;

    // Zero the two halo columns (xp=0,129) once, both buffers, all rows.
    if (tid < 32) {
        const int bufi = tid & 1;
        const int col  = (tid >> 1) & 1;
        const int rc   = tid >> 2;               // 0..7 = r*2+ccl
        bf16x8 z;
        #pragma unroll
        for (int j = 0; j < 8; ++j) z[j] = (bf16)0.0f;
        *(bf16x8*)(ilds + bufi * 8320 + rc * (130 * 8) + (col ? 129 * 8 : 0)) = z;
    }

    float4 pre[8];
    // Issue global loads for a chunk into registers. NO wait here.
    auto issue = [&](int chunk) {
        if (sval) {
            const float* p = sbase + chunk * 16 * HW;
            #pragma unroll
            for (int j = 0; j < 8; ++j) pre[j] = *(const float4*)(p + j * HW);
        }
    };
    // Poly + pack + ds_write (vmcnt wait lands here, after compute).
    auto commit = [&](int buf) {
        bf16x8 pk[4];
        if (sval) {
            #pragma unroll
            for (int x4 = 0; x4 < 4; ++x4)
                #pragma unroll
                for (int j = 0; j < 8; ++j) {
                    float v = ((const float*)&pre[j])[x4];
                    pk[x4][j] = (bf16)(A0 + v * (A1 + A2 * v));
                }
        } else {
            #pragma unroll
            for (int x4 = 0; x4 < 4; ++x4)
                #pragma unroll
                for (int j = 0; j < 8; ++j) pk[x4][j] = (bf16)0.0f;   // conv zero-pad rows
        }
        bf16* dst = srow + buf * 8320;
        #pragma unroll
        for (int x4 = 0; x4 < 4; ++x4) *(bf16x8*)(dst + x4 * 8) = pk[x4];
    };

    f32x16 acc[2][2];
    #pragma unroll
    for (int i = 0; i < 2; ++i)
        #pragma unroll
        for (int j = 0; j < 2; ++j)
            #pragma unroll
            for (int k = 0; k < 16; ++k) acc[i][j][k] = 0.0f;

    const bf16x8* wfr = (const bf16x8*)wrb;

    auto compute = [&](int chunk) {
        const bf16x8* ifr = (const bf16x8*)(ilds + (chunk & 1) * 8320);
        const int cc8g = chunk * 2 + half;
        #pragma unroll
        for (int ky = 0; ky < 3; ++ky) {
            const int r = yl + ky;
            #pragma unroll
            for (int kx = 0; kx < 3; ++kx) {
                const int slice = ky * 3 + kx;
                bf16x8 a0 = wfr[(slice * 8 + cc8g) * 64 + lm];        // weights, L1-hot
                bf16x8 a1 = wfr[(slice * 8 + cc8g) * 64 + 32 + lm];
                const int ib = (r * 2 + half) * 130 + Xh + lm + kx;   // conflict-free b128
                bf16x8 b0 = ifr[ib];
                bf16x8 b1 = ifr[ib + 32];
                acc[0][0] = __builtin_amdgcn_mfma_f32_32x32x16_bf16(a0, b0, acc[0][0], 0, 0, 0);
                acc[0][1] = __builtin_amdgcn_mfma_f32_32x32x16_bf16(a0, b1, acc[0][1], 0, 0, 0);
                acc[1][0] = __builtin_amdgcn_mfma_f32_32x32x16_bf16(a1, b0, acc[1][0], 0, 0, 0);
                acc[1][1] = __builtin_amdgcn_mfma_f32_32x32x16_bf16(a1, b1, acc[1][1], 0, 0, 0);
            }
        }
    };

    // ---- Pipelined K-loop: loads for chunk k fly during compute(k-1). ----
    issue(0);
    #pragma unroll
    for (int chunk = 0; chunk < 4; ++chunk) {
        if (chunk > 0) compute(chunk - 1);   // overlaps in-flight loads of `chunk`
        commit(chunk & 1);                   // waits vmcnt, poly, ds_write
        if (chunk < 3) issue(chunk + 1);     // next loads fly across the barrier
        __syncthreads();
    }
    compute(3);

    // ---- Epilogue: 4 passes of 16 o-rows through LDS, stores as dwordx4. ----
    // C/D layout: col = lane&31 (x), o-in-32 = (rg&3) + 8*(rg>>2) + 4*half.
    #pragma unroll
    for (int p = 0; p < 4; ++p) {
        const int ot  = p >> 1;
        const int sub = p & 1;
        __syncthreads();
        #pragma unroll
        for (int xt = 0; xt < 2; ++xt) {
            const int x = Xh + xt * 32 + lm;
            #pragma unroll
            for (int q = 0; q < 2; ++q)
                #pragma unroll
                for (int rb = 0; rb < 4; ++rb) {
                    const int rg  = (sub * 2 + q) * 4 + rb;
                    const int o16 = rb + 8 * q + 4 * half;          // o-local in [0,16)
                    elds[(o16 * 2 + yl) * 128 + x] = acc[ot][xt][rg];
                }
        }
        __syncthreads();
        #pragma unroll
        for (int j = 0; j < 4; ++j) {
            const int idx = tid + j * 256;          // 1024 float4s = 16 KB
            const int x4  = idx & 31;
            const int y2  = (idx >> 5) & 1;
            const int o16 = idx >> 6;
            float4 v = ((const float4*)elds)[idx];  // lane-contiguous
            *(float4*)(out + ((n * OO + p * 16 + o16) * HH + (y0 + y2)) * WW + 4 * x4) = v;
        }
    }
}

extern "C" void kernel_launch(void* const* d_in, const int* in_sizes, int n_in,
                              void* d_out, int out_size, void* d_ws, size_t ws_size,
                              hipStream_t stream) {
    const float* img = (const float*)d_in[0];
    const float* w   = (const float*)d_in[1];
    // d_in[2] (identity_kernel) unused: its branch convolves exact zeros.
    float* out = (float*)d_out;
    bf16* wrb  = (bf16*)d_ws;    // 36864 bf16 = 73728 B repacked weights

    repack_w<<<(9 * 8 * 64 * 8 + 255) / 256, 256, 0, stream>>>(w, wrb);
    conv_mfma<<<NN * (HH / 2), 256, 0, stream>>>(img, wrb, out);
}